// Round 1
// baseline (320.395 us; speedup 1.0000x reference)
//
#include <hip/hip_runtime.h>
#include <hip/hip_bf16.h>

// Circuit: 4-layer sum-product network, real semiring, f32.
// L0: prod (binary fan-in) over virtual input x = [0, 1, pos0, neg0, ...]
// L1: segment-sum (sorted ix_out), 8M edges -> 1M segs
// L2: prod (binary fan-in)
// L3: segment-sum (sorted ix_out), 1M edges -> 125k segs

__device__ __forceinline__ float decode_input(const float* __restrict__ xp, int idx) {
    // x[0]=0, x[1]=1, x[2+2i]=pos_i, x[3+2i]=1-pos_i
    if (idx < 2) return (float)idx;
    float v = xp[(idx - 2) >> 1];
    return (idx & 1) ? 1.0f - v : v;
}

__global__ void layer0_prod_kernel(const float* __restrict__ x_pos,
                                   const int2* __restrict__ ix,
                                   float* __restrict__ out, int M) {
    int j = blockIdx.x * blockDim.x + threadIdx.x;
    if (j >= M) return;
    int2 p = ix[j];
    out[j] = decode_input(x_pos, p.x) * decode_input(x_pos, p.y);
}

__global__ void prod_kernel(const float* __restrict__ vin,
                            const int2* __restrict__ ix,
                            float* __restrict__ out, int M) {
    int j = blockIdx.x * blockDim.x + threadIdx.x;
    if (j >= M) return;
    int2 p = ix[j];
    out[j] = vin[p.x] * vin[p.y];
}

// Segment sum with sorted segment ids: wave-level segmented inclusive scan,
// then one atomicAdd per segment-run per wave (cross-wave/cross-block runs of
// the same segment are reconciled by the atomic).
__global__ void sum_kernel(const float* __restrict__ vin,
                           const int* __restrict__ ix_in,
                           const int* __restrict__ ix_out,
                           float* __restrict__ out, int nE) {
    int e = blockIdx.x * blockDim.x + threadIdx.x;
    int lane = threadIdx.x & 63;

    int seg = -1;
    float val = 0.0f;
    if (e < nE) {
        seg = ix_out[e];
        val = vin[ix_in[e]];
    }

    // segmented inclusive scan across the 64-lane wave
    #pragma unroll
    for (int off = 1; off < 64; off <<= 1) {
        float v2 = __shfl_up(val, off, 64);
        int   s2 = __shfl_up(seg, off, 64);
        if (lane >= off && s2 == seg) val += v2;
    }

    int seg_next = __shfl_down(seg, 1, 64);
    bool is_last = (lane == 63) || (seg_next != seg);
    if (e < nE && is_last) {
        atomicAdd(&out[seg], val);
    }
}

extern "C" void kernel_launch(void* const* d_in, const int* in_sizes, int n_in,
                              void* d_out, int out_size, void* d_ws, size_t ws_size,
                              hipStream_t stream) {
    const float* x_pos  = (const float*)d_in[0];
    const int*   ix_in0 = (const int*)d_in[1];
    const int*   ix_in1 = (const int*)d_in[2];
    const int*   ix_out1= (const int*)d_in[3];
    const int*   ix_in2 = (const int*)d_in[4];
    const int*   ix_in3 = (const int*)d_in[5];
    const int*   ix_out3= (const int*)d_in[6];
    float* out = (float*)d_out;

    const int M0 = in_sizes[1] / 2;   // 4,000,000
    const int E1 = in_sizes[2];       // 8,000,000
    const int M1 = 1000000;           // layer-1 segment count (fixed by problem)
    const int M2 = in_sizes[4] / 2;   // 500,000
    const int E3 = in_sizes[5];       // 1,000,000
    const int M3 = out_size;          // 125,000

    float* y0 = (float*)d_ws;         // 16 MB
    float* y1 = y0 + M0;              //  4 MB
    float* y2 = y1 + M1;              //  2 MB  (total 22 MB of ws)

    // zero the segment-sum accumulators (ws/out are poisoned before each call)
    hipMemsetAsync(y1,  0, (size_t)M1 * sizeof(float), stream);
    hipMemsetAsync(out, 0, (size_t)M3 * sizeof(float), stream);

    const int B = 256;
    layer0_prod_kernel<<<(M0 + B - 1) / B, B, 0, stream>>>(x_pos, (const int2*)ix_in0, y0, M0);
    sum_kernel        <<<(E1 + B - 1) / B, B, 0, stream>>>(y0, ix_in1, ix_out1, y1, E1);
    prod_kernel       <<<(M2 + B - 1) / B, B, 0, stream>>>(y1, (const int2*)ix_in2, y2, M2);
    sum_kernel        <<<(E3 + B - 1) / B, B, 0, stream>>>(y2, ix_in3, ix_out3, out, E3);
}